// Round 1
// baseline (420.927 us; speedup 1.0000x reference)
//
#include <hip/hip_runtime.h>
#include <hip/hip_bf16.h>

typedef unsigned short u16;
typedef unsigned int u32;
typedef float f32x4 __attribute__((ext_vector_type(4)));
typedef u16 u16x4 __attribute__((ext_vector_type(4)));
typedef u16 u16x8 __attribute__((ext_vector_type(8)));
typedef __bf16 bf16x8 __attribute__((ext_vector_type(8)));

#define OUT_DIM 4096
#define IN_DIM  4096
#define M_DIM   8192   // 4 * 2048

__device__ __forceinline__ u16 f2bf(float f) {
  u32 u = __builtin_bit_cast(u32, f);
  return (u16)((u + 0x7FFFu + ((u >> 16) & 1u)) >> 16);
}

// ---------------------------------------------------------------------------
// W build: codebook gather + sign unpack + 2-level inverse Haar + scale -> bf16
// W layout: [OUT][IN] row-major == B^T layout for the GEMM.
// ---------------------------------------------------------------------------
__global__ __launch_bounds__(256) void build_w_kernel(
    const float* __restrict__ codebook,   // [256][8]
    const float* __restrict__ scales,     // [OUT]
    const int*   __restrict__ indices,    // [OUT*IN/8]
    const int*   __restrict__ signs,      // [OUT*IN/8], 8 bits each (LSB first)
    u16*         __restrict__ W) {
  __shared__ float c[IN_DIM];
  const int o   = blockIdx.x;
  const int tid = threadIdx.x;

  // gather + sign: group g covers c[g*8 .. g*8+7]
  for (int g = tid; g < IN_DIM / 8; g += 256) {
    const int idx = indices[o * (IN_DIM / 8) + g];
    const int sp  = signs[o * (IN_DIM / 8) + g];
    f32x4 c0 = *(const f32x4*)&codebook[idx * 8];
    f32x4 c1 = *(const f32x4*)&codebook[idx * 8 + 4];
    float v[8] = {c0[0], c0[1], c0[2], c0[3], c1[0], c1[1], c1[2], c1[3]};
#pragma unroll
    for (int j = 0; j < 8; ++j)
      c[g * 8 + j] = ((sp >> j) & 1) ? v[j] : -v[j];
  }
  __syncthreads();

  const float scale = scales[o];
  const float S = 0.70710678118654752440f;
  // level-2 inverse Haar, local per t:
  // w[4t+0] = ((c[t]+c[1024+t])*S + c[2048+2t])*S
  // w[4t+1] = ((c[t]+c[1024+t])*S - c[2048+2t])*S
  // w[4t+2] = ((c[t]-c[1024+t])*S + c[2048+2t+1])*S
  // w[4t+3] = ((c[t]-c[1024+t])*S - c[2048+2t+1])*S
  for (int t = tid; t < IN_DIM / 4; t += 256) {
    float a   = c[t];
    float d1  = c[IN_DIM / 4 + t];
    float d2a = c[IN_DIM / 2 + 2 * t];
    float d2b = c[IN_DIM / 2 + 2 * t + 1];
    float e  = (a + d1) * S;
    float od = (a - d1) * S;
    u16x4 w;
    w[0] = f2bf((e  + d2a) * S * scale);
    w[1] = f2bf((e  - d2a) * S * scale);
    w[2] = f2bf((od + d2b) * S * scale);
    w[3] = f2bf((od - d2b) * S * scale);
    *(u16x4*)&W[(size_t)o * IN_DIM + 4 * t] = w;
  }
}

// ---------------------------------------------------------------------------
// X f32 -> bf16 conversion (vectorized, grid-stride)
// ---------------------------------------------------------------------------
__global__ __launch_bounds__(256) void cvt_x_kernel(
    const float* __restrict__ X, u16* __restrict__ Xb) {
  const int stride = gridDim.x * blockDim.x;
  const int n8 = (M_DIM * IN_DIM) / 8;
  for (int i = blockIdx.x * blockDim.x + threadIdx.x; i < n8; i += stride) {
    f32x4 a = *(const f32x4*)&X[(size_t)i * 8];
    f32x4 b = *(const f32x4*)&X[(size_t)i * 8 + 4];
    u16x8 r;
    r[0] = f2bf(a[0]); r[1] = f2bf(a[1]); r[2] = f2bf(a[2]); r[3] = f2bf(a[3]);
    r[4] = f2bf(b[0]); r[5] = f2bf(b[1]); r[6] = f2bf(b[2]); r[7] = f2bf(b[3]);
    *(u16x8*)&Xb[(size_t)i * 8] = r;
  }
}

// ---------------------------------------------------------------------------
// GEMM: C[M][N] f32 = A[M][K](bf16) x B[N][K](bf16, B^T layout), K summed.
// 128x128 tile, BK=32, 4 waves (2x2), each wave 64x64 via 4x4 mfma 16x16x32.
// global_load_lds width=16 staging, double-buffered LDS, XCD swizzle.
// ---------------------------------------------------------------------------
__global__ __launch_bounds__(256) void gemm_bt_kernel(
    const u16* __restrict__ A,   // [M_DIM][K] bf16 bits
    const u16* __restrict__ B,   // [OUT_DIM][K] bf16 bits
    float*     __restrict__ C) { // [M_DIM][OUT_DIM]
  constexpr int K = IN_DIM;
  __shared__ __align__(16) u16 lds[2][2][128 * 32];

  const int tid  = threadIdx.x;
  const int wave = tid >> 6;
  const int lane = tid & 63;

  // XCD-aware bijective swizzle (grid = 2048, divisible by 8)
  const int cpx = gridDim.x >> 3;
  const int swz = (blockIdx.x & 7) * cpx + (blockIdx.x >> 3);
  const int bm = (swz >> 5) * 128;   // 64 row-blocks
  const int bn = (swz & 31) * 128;   // 32 col-blocks

  const int wr = (wave >> 1) * 64;
  const int wc = (wave & 1) * 64;
  const int fr = lane & 15;
  const int fk = (lane >> 4) * 8;

  f32x4 acc[4][4] = {};

  auto stage = [&](int buf, int kt) {
    const int k0 = kt * 32;
#pragma unroll
    for (int s = 0; s < 2; ++s) {
      const int e = (s * 256 + tid) * 8;  // flat bf16 element within 128x32 tile
      const int r = e >> 5, cc = e & 31;
      const u16* gA = A + (size_t)(bm + r) * K + k0 + cc;
      const u16* gB = B + (size_t)(bn + r) * K + k0 + cc;
      u16* lA = &lds[buf][0][(s * 256 + wave * 64) * 8];  // wave-uniform base
      u16* lB = &lds[buf][1][(s * 256 + wave * 64) * 8];
      __builtin_amdgcn_global_load_lds(
          (const __attribute__((address_space(1))) void*)gA,
          (__attribute__((address_space(3))) void*)lA, 16, 0, 0);
      __builtin_amdgcn_global_load_lds(
          (const __attribute__((address_space(1))) void*)gB,
          (__attribute__((address_space(3))) void*)lB, 16, 0, 0);
    }
  };

  stage(0, 0);
  int cur = 0;
  const int NT = K / 32;  // 128
  for (int kt = 0; kt < NT; ++kt) {
    __syncthreads();  // staged data for lds[cur] arrived; prior reads of lds[cur^1] done
    if (kt + 1 < NT) stage(cur ^ 1, kt + 1);
    bf16x8 af[4], bfv[4];
#pragma unroll
    for (int m = 0; m < 4; ++m)
      af[m] = *(const bf16x8*)&lds[cur][0][(wr + m * 16 + fr) * 32 + fk];
#pragma unroll
    for (int n = 0; n < 4; ++n)
      bfv[n] = *(const bf16x8*)&lds[cur][1][(wc + n * 16 + fr) * 32 + fk];
#pragma unroll
    for (int m = 0; m < 4; ++m)
#pragma unroll
      for (int n = 0; n < 4; ++n)
        acc[m][n] = __builtin_amdgcn_mfma_f32_16x16x32_bf16(af[m], bfv[n], acc[m][n], 0, 0, 0);
    cur ^= 1;
  }

  // epilogue: C/D layout col=lane&15, row=(lane>>4)*4+j  (m89-verified)
#pragma unroll
  for (int m = 0; m < 4; ++m) {
#pragma unroll
    for (int n = 0; n < 4; ++n) {
      const int col = bn + wc + n * 16 + fr;
#pragma unroll
      for (int j = 0; j < 4; ++j) {
        const int row = bm + wr + m * 16 + (lane >> 4) * 4 + j;
        C[(size_t)row * OUT_DIM + col] = acc[m][n][j];
      }
    }
  }
}

// ---------------------------------------------------------------------------
extern "C" void kernel_launch(void* const* d_in, const int* in_sizes, int n_in,
                              void* d_out, int out_size, void* d_ws, size_t ws_size,
                              hipStream_t stream) {
  const float* x        = (const float*)d_in[0];  // [4][2048][IN] f32
  const float* codebook = (const float*)d_in[1];  // [256][8] f32
  const float* scales   = (const float*)d_in[2];  // [OUT][1] f32
  const int*   indices  = (const int*)d_in[3];    // [OUT*IN/8] i32
  const int*   signs    = (const int*)d_in[4];    // [OUT*IN/8] i32
  float* out = (float*)d_out;                     // [M_DIM][OUT] f32

  u16* W  = (u16*)d_ws;                                   // 4096*4096 bf16 = 32 MiB
  u16* Xb = (u16*)d_ws + (size_t)OUT_DIM * IN_DIM;        // 8192*4096 bf16 = 64 MiB

  build_w_kernel<<<OUT_DIM, 256, 0, stream>>>(codebook, scales, indices, signs, W);
  cvt_x_kernel<<<2048, 256, 0, stream>>>(x, Xb);
  gemm_bt_kernel<<<(M_DIM / 128) * (OUT_DIM / 128), 256, 0, stream>>>(Xb, W, out);
}

// Round 2
// 301.548 us; speedup vs baseline: 1.3959x; 1.3959x over previous
//
#include <hip/hip_runtime.h>
#include <hip/hip_bf16.h>

typedef unsigned short u16;
typedef unsigned int u32;
typedef float f32x4 __attribute__((ext_vector_type(4)));
typedef u16 u16x4 __attribute__((ext_vector_type(4)));
typedef u16 u16x8 __attribute__((ext_vector_type(8)));
typedef __bf16 bf16x8 __attribute__((ext_vector_type(8)));

#define OUT_DIM 4096
#define IN_DIM  4096
#define M_DIM   8192   // 4 * 2048

__device__ __forceinline__ u16 f2bf(float f) {
  u32 u = __builtin_bit_cast(u32, f);
  return (u16)((u + 0x7FFFu + ((u >> 16) & 1u)) >> 16);
}

// ---------------------------------------------------------------------------
// W build: codebook gather + sign unpack + 2-level inverse Haar + scale -> bf16
// ---------------------------------------------------------------------------
__global__ __launch_bounds__(256) void build_w_kernel(
    const float* __restrict__ codebook, const float* __restrict__ scales,
    const int* __restrict__ indices, const int* __restrict__ signs,
    u16* __restrict__ W) {
  __shared__ float c[IN_DIM];
  const int o   = blockIdx.x;
  const int tid = threadIdx.x;
  for (int g = tid; g < IN_DIM / 8; g += 256) {
    const int idx = indices[o * (IN_DIM / 8) + g];
    const int sp  = signs[o * (IN_DIM / 8) + g];
    f32x4 c0 = *(const f32x4*)&codebook[idx * 8];
    f32x4 c1 = *(const f32x4*)&codebook[idx * 8 + 4];
    float v[8] = {c0[0], c0[1], c0[2], c0[3], c1[0], c1[1], c1[2], c1[3]};
#pragma unroll
    for (int j = 0; j < 8; ++j)
      c[g * 8 + j] = ((sp >> j) & 1) ? v[j] : -v[j];
  }
  __syncthreads();
  const float scale = scales[o];
  const float S = 0.70710678118654752440f;
  for (int t = tid; t < IN_DIM / 4; t += 256) {
    float a   = c[t];
    float d1  = c[IN_DIM / 4 + t];
    float d2a = c[IN_DIM / 2 + 2 * t];
    float d2b = c[IN_DIM / 2 + 2 * t + 1];
    float e  = (a + d1) * S;
    float od = (a - d1) * S;
    u16x4 w;
    w[0] = f2bf((e  + d2a) * S * scale);
    w[1] = f2bf((e  - d2a) * S * scale);
    w[2] = f2bf((od + d2b) * S * scale);
    w[3] = f2bf((od - d2b) * S * scale);
    *(u16x4*)&W[(size_t)o * IN_DIM + 4 * t] = w;
  }
}

// ---------------------------------------------------------------------------
// X f32 -> bf16
// ---------------------------------------------------------------------------
__global__ __launch_bounds__(256) void cvt_x_kernel(
    const float* __restrict__ X, u16* __restrict__ Xb) {
  const int stride = gridDim.x * blockDim.x;
  const int n8 = (M_DIM * IN_DIM) / 8;
  for (int i = blockIdx.x * blockDim.x + threadIdx.x; i < n8; i += stride) {
    f32x4 a = *(const f32x4*)&X[(size_t)i * 8];
    f32x4 b = *(const f32x4*)&X[(size_t)i * 8 + 4];
    u16x8 r;
    r[0] = f2bf(a[0]); r[1] = f2bf(a[1]); r[2] = f2bf(a[2]); r[3] = f2bf(a[3]);
    r[4] = f2bf(b[0]); r[5] = f2bf(b[1]); r[6] = f2bf(b[2]); r[7] = f2bf(b[3]);
    *(u16x8*)&Xb[(size_t)i * 8] = r;
  }
}

// ---------------------------------------------------------------------------
// GEMM: C[M][N] f32 = A[M][K](bf16) x B[N][K](bf16, B^T layout).
// 256x256 tile, BK=32, 8 waves (2Mx4N), 4-deep LDS ring (128 KiB dynamic),
// counted-vmcnt pipeline (T3/T4), XOR bank swizzle (T2), setprio (T5),
// XCD swizzle (T1).
// LDS buffer b (32 KiB): A region [256 rows][64 B] then B region.
// Swizzle involution on byte offset within region: o ^= ((o>>3)&0x30)
//   (16B-slot index ^= (row>>1)&3) -> 2-way residual conflict (free).
// ---------------------------------------------------------------------------
__global__ __launch_bounds__(512) void gemm_bt_kernel(
    const u16* __restrict__ A,   // [M_DIM][K]
    const u16* __restrict__ B,   // [OUT_DIM][K]
    float*     __restrict__ C) { // [M_DIM][OUT_DIM]
  constexpr int K    = IN_DIM;
  constexpr int NT   = K / 32;     // 128 K-tiles
  constexpr int BUFB = 32768;      // bytes per ring buffer
  extern __shared__ char smem[];

  const int tid  = threadIdx.x;
  const int wave = tid >> 6;
  const int lane = tid & 63;

  // XCD-aware bijective swizzle (grid = 512, 512 % 8 == 0)
  const int swz = (blockIdx.x & 7) * 64 + (blockIdx.x >> 3);
  const int bm = (swz >> 4) * 256;   // 32 M-blocks
  const int bn = (swz & 15) * 256;   // 16 N-blocks

  const int wr  = (wave >> 2) * 128;  // wave M offset in tile
  const int wc  = (wave & 3) * 64;    // wave N offset in tile
  const int fr  = lane & 15;
  const int fkB = (lane >> 4) * 16;   // k-fragment byte offset in row

  // loop-invariant swizzled read offsets
  int offA[8], offB[4];
#pragma unroll
  for (int h = 0; h < 8; ++h) {
    int o = (wr + h * 16 + fr) * 64 + fkB;
    offA[h] = o ^ ((o >> 3) & 0x30);
  }
#pragma unroll
  for (int n = 0; n < 4; ++n) {
    int o = (wc + n * 16 + fr) * 64 + fkB;
    offB[n] = 16384 + (o ^ ((o >> 3) & 0x30));
  }

  // per-thread pre-swizzled global stage sources (inverse of read swizzle)
  const u16* srcA[2]; const u16* srcB[2];
#pragma unroll
  for (int i = 0; i < 2; ++i) {
    int d = i * 8192 + tid * 16;            // linear LDS dest byte
    int l = d ^ ((d >> 3) & 0x30);          // logical byte -> global column
    int row = d >> 6;
    srcA[i] = A + (size_t)(bm + row) * K + ((l & 63) >> 1);
    srcB[i] = B + (size_t)(bn + row) * K + ((l & 63) >> 1);
  }
  const int ldsW = wave * 1024;  // wave-uniform dest base (HW adds lane*16)

  f32x4 acc[8][4] = {};

  auto stageA = [&](int tt) {
    char* base = smem + (tt & 3) * BUFB + ldsW;
#pragma unroll
    for (int i = 0; i < 2; ++i)
      __builtin_amdgcn_global_load_lds(
          (const __attribute__((address_space(1))) void*)(srcA[i] + tt * 32),
          (__attribute__((address_space(3))) void*)(base + i * 8192), 16, 0, 0);
  };
  auto stageB = [&](int tt) {
    char* base = smem + (tt & 3) * BUFB + 16384 + ldsW;
#pragma unroll
    for (int i = 0; i < 2; ++i)
      __builtin_amdgcn_global_load_lds(
          (const __attribute__((address_space(1))) void*)(srcB[i] + tt * 32),
          (__attribute__((address_space(3))) void*)(base + i * 8192), 16, 0, 0);
  };

  // prologue: stage tiles 0,1,2 (12 loads); wait tile 0 (allow 8 newer)
  stageA(0); stageB(0); stageA(1); stageB(1); stageA(2); stageB(2);
  asm volatile("s_waitcnt vmcnt(8)" ::: "memory");
  __builtin_amdgcn_s_barrier();

  for (int t = 0; t < NT; ++t) {
    const char* buf = smem + (t & 3) * BUFB;
    bf16x8 bfv[4], af[4];
    // ---- phase A: read B-frags + A(mh=0); stage A-half of tile t+3
#pragma unroll
    for (int n = 0; n < 4; ++n) bfv[n] = *(const bf16x8*)(buf + offB[n]);
#pragma unroll
    for (int m = 0; m < 4; ++m) af[m] = *(const bf16x8*)(buf + offA[m]);
    if (t + 3 < NT) stageA(t + 3);
    __builtin_amdgcn_s_barrier();
    __builtin_amdgcn_s_setprio(1);
#pragma unroll
    for (int m = 0; m < 4; ++m)
#pragma unroll
      for (int n = 0; n < 4; ++n)
        acc[m][n] = __builtin_amdgcn_mfma_f32_16x16x32_bf16(af[m], bfv[n], acc[m][n], 0, 0, 0);
    __builtin_amdgcn_s_setprio(0);
    __builtin_amdgcn_s_barrier();
    // ---- phase B: read A(mh=1); stage B-half of tile t+3
#pragma unroll
    for (int m = 0; m < 4; ++m) af[m] = *(const bf16x8*)(buf + offA[4 + m]);
    if (t + 3 < NT) stageB(t + 3);
    __builtin_amdgcn_s_barrier();
    __builtin_amdgcn_s_setprio(1);
#pragma unroll
    for (int m = 0; m < 4; ++m)
#pragma unroll
      for (int n = 0; n < 4; ++n)
        acc[4 + m][n] = __builtin_amdgcn_mfma_f32_16x16x32_bf16(af[m], bfv[n], acc[4 + m][n], 0, 0, 0);
    __builtin_amdgcn_s_setprio(0);
    // gate for tile t+1: allow the 2 newer tiles' loads (8) to stay in flight
    if (t + 3 < NT)      asm volatile("s_waitcnt vmcnt(8)" ::: "memory");
    else if (t + 2 < NT) asm volatile("s_waitcnt vmcnt(4)" ::: "memory");
    else                 asm volatile("s_waitcnt vmcnt(0)" ::: "memory");
    __builtin_amdgcn_s_barrier();
  }

  // epilogue: C/D layout col=lane&15, row=(lane>>4)*4+j (m89-verified)
#pragma unroll
  for (int h = 0; h < 8; ++h)
#pragma unroll
    for (int n = 0; n < 4; ++n) {
      const int col = bn + wc + n * 16 + fr;
#pragma unroll
      for (int j = 0; j < 4; ++j) {
        const int row = bm + wr + h * 16 + (lane >> 4) * 4 + j;
        C[(size_t)row * OUT_DIM + col] = acc[h][n][j];
      }
    }
}

// ---------------------------------------------------------------------------
extern "C" void kernel_launch(void* const* d_in, const int* in_sizes, int n_in,
                              void* d_out, int out_size, void* d_ws, size_t ws_size,
                              hipStream_t stream) {
  const float* x        = (const float*)d_in[0];
  const float* codebook = (const float*)d_in[1];
  const float* scales   = (const float*)d_in[2];
  const int*   indices  = (const int*)d_in[3];
  const int*   signs    = (const int*)d_in[4];
  float* out = (float*)d_out;

  u16* W  = (u16*)d_ws;
  u16* Xb = (u16*)d_ws + (size_t)OUT_DIM * IN_DIM;

  (void)hipFuncSetAttribute((const void*)gemm_bt_kernel,
                            hipFuncAttributeMaxDynamicSharedMemorySize, 131072);

  build_w_kernel<<<OUT_DIM, 256, 0, stream>>>(codebook, scales, indices, signs, W);
  cvt_x_kernel<<<2048, 256, 0, stream>>>(x, Xb);
  gemm_bt_kernel<<<(M_DIM / 256) * (OUT_DIM / 256), 512, 131072, stream>>>(Xb, W, out);
}

// Round 3
// 295.663 us; speedup vs baseline: 1.4237x; 1.0199x over previous
//
#include <hip/hip_runtime.h>
#include <hip/hip_bf16.h>

typedef unsigned short u16;
typedef unsigned int u32;
typedef float f32x4 __attribute__((ext_vector_type(4)));
typedef u16 u16x4 __attribute__((ext_vector_type(4)));
typedef u16 u16x8 __attribute__((ext_vector_type(8)));
typedef __bf16 bf16x8 __attribute__((ext_vector_type(8)));

#define OUT_DIM 4096
#define IN_DIM  4096
#define M_DIM   8192   // 4 * 2048

__device__ __forceinline__ u16 f2bf(float f) {
  u32 u = __builtin_bit_cast(u32, f);
  return (u16)((u + 0x7FFFu + ((u >> 16) & 1u)) >> 16);
}

// ---------------------------------------------------------------------------
// W build: codebook gather + sign unpack + 2-level inverse Haar + scale -> bf16
// ---------------------------------------------------------------------------
__global__ __launch_bounds__(256) void build_w_kernel(
    const float* __restrict__ codebook, const float* __restrict__ scales,
    const int* __restrict__ indices, const int* __restrict__ signs,
    u16* __restrict__ W) {
  __shared__ float c[IN_DIM];
  const int o   = blockIdx.x;
  const int tid = threadIdx.x;
  for (int g = tid; g < IN_DIM / 8; g += 256) {
    const int idx = indices[o * (IN_DIM / 8) + g];
    const int sp  = signs[o * (IN_DIM / 8) + g];
    f32x4 c0 = *(const f32x4*)&codebook[idx * 8];
    f32x4 c1 = *(const f32x4*)&codebook[idx * 8 + 4];
    float v[8] = {c0[0], c0[1], c0[2], c0[3], c1[0], c1[1], c1[2], c1[3]};
#pragma unroll
    for (int j = 0; j < 8; ++j)
      c[g * 8 + j] = ((sp >> j) & 1) ? v[j] : -v[j];
  }
  __syncthreads();
  const float scale = scales[o];
  const float S = 0.70710678118654752440f;
  for (int t = tid; t < IN_DIM / 4; t += 256) {
    float a   = c[t];
    float d1  = c[IN_DIM / 4 + t];
    float d2a = c[IN_DIM / 2 + 2 * t];
    float d2b = c[IN_DIM / 2 + 2 * t + 1];
    float e  = (a + d1) * S;
    float od = (a - d1) * S;
    u16x4 w;
    w[0] = f2bf((e  + d2a) * S * scale);
    w[1] = f2bf((e  - d2a) * S * scale);
    w[2] = f2bf((od + d2b) * S * scale);
    w[3] = f2bf((od - d2b) * S * scale);
    *(u16x4*)&W[(size_t)o * IN_DIM + 4 * t] = w;
  }
}

// ---------------------------------------------------------------------------
// X f32 -> bf16
// ---------------------------------------------------------------------------
__global__ __launch_bounds__(256) void cvt_x_kernel(
    const float* __restrict__ X, u16* __restrict__ Xb) {
  const int stride = gridDim.x * blockDim.x;
  const int n8 = (M_DIM * IN_DIM) / 8;
  for (int i = blockIdx.x * blockDim.x + threadIdx.x; i < n8; i += stride) {
    f32x4 a = *(const f32x4*)&X[(size_t)i * 8];
    f32x4 b = *(const f32x4*)&X[(size_t)i * 8 + 4];
    u16x8 r;
    r[0] = f2bf(a[0]); r[1] = f2bf(a[1]); r[2] = f2bf(a[2]); r[3] = f2bf(a[3]);
    r[4] = f2bf(b[0]); r[5] = f2bf(b[1]); r[6] = f2bf(b[2]); r[7] = f2bf(b[3]);
    *(u16x8*)&Xb[(size_t)i * 8] = r;
  }
}

// ---------------------------------------------------------------------------
// GEMM: C[M][N] f32 = A[M][K](bf16) x B[N][K](bf16, B^T layout).
// 256x256 tile, BK=32, 8 waves (2Mx4N), 4-deep LDS ring (128 KiB dynamic).
// R3: register-pipelined fragment reads (RD one phase ahead, counted-lgkm by
// compiler), gate moved to end of phase A with proven vmcnt(6/4/0).
// ---------------------------------------------------------------------------
__global__ __launch_bounds__(512, 2) void gemm_bt_kernel(
    const u16* __restrict__ A,   // [M_DIM][K]
    const u16* __restrict__ B,   // [OUT_DIM][K]
    float*     __restrict__ C) { // [M_DIM][OUT_DIM]
  constexpr int K    = IN_DIM;
  constexpr int NT   = K / 32;     // 128 K-tiles
  constexpr int BUFB = 32768;      // bytes per ring buffer
  extern __shared__ char smem[];

  const int tid  = threadIdx.x;
  const int wave = tid >> 6;
  const int lane = tid & 63;

  // XCD-aware bijective swizzle (grid = 512, 512 % 8 == 0)
  const int swz = (blockIdx.x & 7) * 64 + (blockIdx.x >> 3);
  const int bm = (swz >> 4) * 256;   // 32 M-blocks
  const int bn = (swz & 15) * 256;   // 16 N-blocks

  const int wr  = (wave >> 2) * 128;  // wave M offset in tile
  const int wc  = (wave & 3) * 64;    // wave N offset in tile
  const int fr  = lane & 15;
  const int fkB = (lane >> 4) * 16;   // k-fragment byte offset in row

  // loop-invariant swizzled read offsets (involution: slot ^= (row>>1)&3)
  int offA[8], offB[4];
#pragma unroll
  for (int h = 0; h < 8; ++h) {
    int o = (wr + h * 16 + fr) * 64 + fkB;
    offA[h] = o ^ ((o >> 3) & 0x30);
  }
#pragma unroll
  for (int n = 0; n < 4; ++n) {
    int o = (wc + n * 16 + fr) * 64 + fkB;
    offB[n] = 16384 + (o ^ ((o >> 3) & 0x30));
  }

  // per-thread pre-swizzled global stage sources (inverse of read swizzle)
  const u16* srcA[2]; const u16* srcB[2];
#pragma unroll
  for (int i = 0; i < 2; ++i) {
    int d = i * 8192 + tid * 16;            // linear LDS dest byte
    int l = d ^ ((d >> 3) & 0x30);          // logical byte -> global column
    int row = d >> 6;
    srcA[i] = A + (size_t)(bm + row) * K + ((l & 63) >> 1);
    srcB[i] = B + (size_t)(bn + row) * K + ((l & 63) >> 1);
  }
  const int ldsW = wave * 1024;  // wave-uniform dest base (HW adds lane*16)

  auto stageA = [&](int tt) {
    char* base = smem + (tt & 3) * BUFB + ldsW;
#pragma unroll
    for (int i = 0; i < 2; ++i)
      __builtin_amdgcn_global_load_lds(
          (const __attribute__((address_space(1))) void*)(srcA[i] + tt * 32),
          (__attribute__((address_space(3))) void*)(base + i * 8192), 16, 0, 0);
  };
  auto stageB = [&](int tt) {
    char* base = smem + (tt & 3) * BUFB + 16384 + ldsW;
#pragma unroll
    for (int i = 0; i < 2; ++i)
      __builtin_amdgcn_global_load_lds(
          (const __attribute__((address_space(1))) void*)(srcB[i] + tt * 32),
          (__attribute__((address_space(3))) void*)(base + i * 8192), 16, 0, 0);
  };

  f32x4 acc[8][4] = {};
  bf16x8 aloX[4], bX[4], aloY[4], bY[4], ahi[4];

  // prologue: stage tiles 0,1,2 (12 loads); ensure tile 0 landed (leave 8)
  stageA(0); stageB(0); stageA(1); stageB(1); stageA(2); stageB(2);
  asm volatile("s_waitcnt vmcnt(8)" ::: "memory");
  __builtin_amdgcn_s_barrier();
  {
    const char* buf0 = smem;
#pragma unroll
    for (int n = 0; n < 4; ++n) bX[n]   = *(const bf16x8*)(buf0 + offB[n]);
#pragma unroll
    for (int m = 0; m < 4; ++m) aloX[m] = *(const bf16x8*)(buf0 + offA[m]);
  }

  // tile body: cur frags (cA/cB) were read last phase; read ahi now (flies
  // during MFMA-A) and next tile's frags in phase B (flies during MFMA-B).
  auto tile = [&](int t, bf16x8 (&cA)[4], bf16x8 (&cB)[4],
                  bf16x8 (&nA)[4], bf16x8 (&nB)[4]) {
    const char* buf  = smem + (t & 3) * BUFB;
    const char* bufn = smem + ((t + 1) & 3) * BUFB;
    // ---- phase A
    if (t + 3 < NT) stageA(t + 3);
#pragma unroll
    for (int m = 0; m < 4; ++m) ahi[m] = *(const bf16x8*)(buf + offA[4 + m]);
    __builtin_amdgcn_s_setprio(1);
#pragma unroll
    for (int m = 0; m < 4; ++m)
#pragma unroll
      for (int n = 0; n < 4; ++n)
        acc[m][n] = __builtin_amdgcn_mfma_f32_16x16x32_bf16(cA[m], cB[n], acc[m][n], 0, 0, 0);
    __builtin_amdgcn_s_setprio(0);
    // gate: staged(t+1) must be retired before RD of tile t+1 in phase B.
    // outstanding after gate (steady): A(t+2),B(t+2),A(t+3) = 6 loads.
    if (t + 3 < NT)       asm volatile("s_waitcnt vmcnt(6)" ::: "memory");
    else if (t + 3 == NT) asm volatile("s_waitcnt vmcnt(4)" ::: "memory");
    else if (t + 2 == NT) asm volatile("s_waitcnt vmcnt(0)" ::: "memory");
    __builtin_amdgcn_s_barrier();
    // ---- phase B
    if (t + 3 < NT) stageB(t + 3);
    if (t + 1 < NT) {
#pragma unroll
      for (int n = 0; n < 4; ++n) nB[n] = *(const bf16x8*)(bufn + offB[n]);
#pragma unroll
      for (int m = 0; m < 4; ++m) nA[m] = *(const bf16x8*)(bufn + offA[m]);
    }
    __builtin_amdgcn_s_setprio(1);
#pragma unroll
    for (int m = 0; m < 4; ++m)
#pragma unroll
      for (int n = 0; n < 4; ++n)
        acc[4 + m][n] = __builtin_amdgcn_mfma_f32_16x16x32_bf16(ahi[m], cB[n], acc[4 + m][n], 0, 0, 0);
    __builtin_amdgcn_s_setprio(0);
    __builtin_amdgcn_s_barrier();
  };

  for (int t = 0; t < NT; t += 2) {
    tile(t,     aloX, bX, aloY, bY);
    tile(t + 1, aloY, bY, aloX, bX);
  }

  // epilogue: C/D layout col=lane&15, row=(lane>>4)*4+j (m89-verified)
#pragma unroll
  for (int h = 0; h < 8; ++h)
#pragma unroll
    for (int n = 0; n < 4; ++n) {
      const int col = bn + wc + n * 16 + fr;
#pragma unroll
      for (int j = 0; j < 4; ++j) {
        const int row = bm + wr + h * 16 + (lane >> 4) * 4 + j;
        C[(size_t)row * OUT_DIM + col] = acc[h][n][j];
      }
    }
}

// ---------------------------------------------------------------------------
extern "C" void kernel_launch(void* const* d_in, const int* in_sizes, int n_in,
                              void* d_out, int out_size, void* d_ws, size_t ws_size,
                              hipStream_t stream) {
  const float* x        = (const float*)d_in[0];
  const float* codebook = (const float*)d_in[1];
  const float* scales   = (const float*)d_in[2];
  const int*   indices  = (const int*)d_in[3];
  const int*   signs    = (const int*)d_in[4];
  float* out = (float*)d_out;

  u16* W  = (u16*)d_ws;
  u16* Xb = (u16*)d_ws + (size_t)OUT_DIM * IN_DIM;

  (void)hipFuncSetAttribute((const void*)gemm_bt_kernel,
                            hipFuncAttributeMaxDynamicSharedMemorySize, 131072);

  build_w_kernel<<<OUT_DIM, 256, 0, stream>>>(codebook, scales, indices, signs, W);
  cvt_x_kernel<<<2048, 256, 0, stream>>>(x, Xb);
  gemm_bt_kernel<<<(M_DIM / 256) * (OUT_DIM / 256), 512, 131072, stream>>>(Xb, W, out);
}